// Round 6
// baseline (925.910 us; speedup 1.0000x reference)
//
#include <hip/hip_runtime.h>
#include <hip/hip_bf16.h>

#define B_ROWS   4096
#define L_LABELS 100000
#define L_PAD    100032   // 1563 * 64, padded with zero rows
#define PADROWS  32
#define D_DIM    256
#define TOPK     5
#define SLABN    64       // labels per slab
#define NSLAB    1563     // L_PAD / SLABN
#define NGROUP   32       // label groups (grid.x) -> XCD x%8

typedef __bf16 bf16x8 __attribute__((ext_vector_type(8)));
typedef __bf16 bf16x4 __attribute__((ext_vector_type(4)));
typedef float  f32x4  __attribute__((ext_vector_type(4)));

__device__ __forceinline__ void async16(const void* g, void* l) {
    __builtin_amdgcn_global_load_lds(
        (const __attribute__((address_space(1))) unsigned int*)g,
        (__attribute__((address_space(3))) unsigned int*)l,
        16, 0, 0);
}

// ---------------------------------------------------------------------------
// fp32 -> bf16 converters
// ---------------------------------------------------------------------------
__global__ void convertP_kernel(const float* __restrict__ src,
                                __hip_bfloat16* __restrict__ dst) {
    size_t i = ((size_t)blockIdx.x * blockDim.x + threadIdx.x) * 8;
    float4 a = *(const float4*)(src + i);
    float4 b = *(const float4*)(src + i + 4);
    bf16x8 v = {(__bf16)a.x, (__bf16)a.y, (__bf16)a.z, (__bf16)a.w,
                (__bf16)b.x, (__bf16)b.y, (__bf16)b.z, (__bf16)b.w};
    *(bf16x8*)((__bf16*)dst + i) = v;
}

__global__ void convertL_kernel(const float* __restrict__ src,
                                __hip_bfloat16* __restrict__ dst) {
    size_t i = ((size_t)blockIdx.x * blockDim.x + threadIdx.x) * 8;
    bf16x8 v;
    if (i < (size_t)L_LABELS * D_DIM) {
        float4 a = *(const float4*)(src + i);
        float4 b = *(const float4*)(src + i + 4);
        v = (bf16x8){(__bf16)a.x, (__bf16)a.y, (__bf16)a.z, (__bf16)a.w,
                     (__bf16)b.x, (__bf16)b.y, (__bf16)b.z, (__bf16)b.w};
    } else {
        v = (bf16x8){(__bf16)0.f, (__bf16)0.f, (__bf16)0.f, (__bf16)0.f,
                     (__bf16)0.f, (__bf16)0.f, (__bf16)0.f, (__bf16)0.f};
    }
    *(bf16x8*)((__bf16*)dst + i) = v;
}

// ---------------------------------------------------------------------------
// Kernel 1: per-row threshold s_t (bf16-rounded inputs) + zero counters.
// ---------------------------------------------------------------------------
__global__ void prep_kernel(const float* __restrict__ P,
                            const float* __restrict__ Lab,
                            const int*   __restrict__ labels,
                            float* __restrict__ s_t,
                            int*   __restrict__ counts) {
    int gwave = (blockIdx.x * blockDim.x + threadIdx.x) >> 6;
    int lane  = threadIdx.x & 63;
    if (gwave >= B_ROWS) return;
    int t = labels[gwave];
    const float4* p4 = (const float4*)(P + (size_t)gwave * D_DIM);
    const float4* l4 = (const float4*)(Lab + (size_t)t * D_DIM);
    float4 a = p4[lane];
    float4 b = l4[lane];
    float sum = 0.f;
    sum += (float)(__bf16)a.x * (float)(__bf16)b.x;
    sum += (float)(__bf16)a.y * (float)(__bf16)b.y;
    sum += (float)(__bf16)a.z * (float)(__bf16)b.z;
    sum += (float)(__bf16)a.w * (float)(__bf16)b.w;
    #pragma unroll
    for (int m = 1; m < 64; m <<= 1) sum += __shfl_xor(sum, m, 64);
    if (lane == 0) {
        s_t[gwave]    = sum;
        counts[gwave] = 0;
    }
}

// ---------------------------------------------------------------------------
// Kernel 2 (v6): fat-wave count GEMM.
// Block = 256 thr = 4 waves, ONE wave per SIMD (__launch_bounds__(256,1)
// -> 512 VGPR budget). Each wave holds 128 A-rows x K=256 stationary in
// registers (af[8][8] = 256 VGPR) -> every 1KB LDS B-fragment feeds 8 MFMAs.
// B: 64-label slabs (32 KB) double-buffered in LDS via global_load_lds DMA
// (no ds_write, no staging VGPRs). Barrier once per slab (~5000 cyc of MFMA);
// DMA for slab s+1 issued right after the barrier -> full-slab overlap window.
// Source-side XOR chunk swizzle: LDS slot (row,qc) holds global chunk
// (qc&24)|((qc^row)&7); frag ds_read_b128 then lands uniformly on all 8
// bank-groups (8 lanes each = even = conflict-free).
// Pad labels contribute exactly +0.0f; corrected in finalize (R4-proven).
// ---------------------------------------------------------------------------
__global__ __launch_bounds__(256, 1)
void count_kernel_v6(const __hip_bfloat16* __restrict__ Pb,
                     const __hip_bfloat16* __restrict__ Lb,
                     const int*   __restrict__ labels,
                     const float* __restrict__ s_t,
                     int* __restrict__ counts) {
    __shared__ __align__(16) __bf16 Bs[2 * SLABN * D_DIM];   // 2 x 32 KB

    const int group = blockIdx.x;            // 0..31 -> XCD group%8
    const int tid   = threadIdx.x;
    const int wave  = tid >> 6;              // 0..3
    const int lane  = tid & 63;
    const int quad  = lane >> 4;             // 0..3
    const int cc    = lane & 15;             // 0..15
    const int Mbase = blockIdx.y * 512 + wave * 128;

    const int s0 = (group * NSLAB) / NGROUP;
    const int s1 = ((group + 1) * NSLAB) / NGROUP;

    // per-thread DMA source offset (bytes within a slab), 8 instr/wave
    int dma_off[8];
    #pragma unroll
    for (int j = 0; j < 8; ++j) {
        int c   = wave * 512 + j * 64 + lane;   // LDS chunk 0..2047
        int row = c >> 5;                       // label row 0..63
        int qc  = c & 31;
        int gc  = (qc & 24) | ((qc ^ row) & 7);
        dma_off[j] = row * 512 + gc * 16;
    }

    // ---- issue DMA for first slab into buffer 0 ----
    {
        const char* gbase = (const char*)Lb + (size_t)s0 * (SLABN * D_DIM * 2);
        #pragma unroll
        for (int j = 0; j < 8; ++j)
            async16(gbase + dma_off[j],
                    (char*)Bs + (size_t)(wave * 512 + j * 64) * 16);
    }

    // ---- stationary A fragments: 128 rows x K=256 (256 VGPR) ----
    bf16x8 af[8][8];
    #pragma unroll
    for (int mi = 0; mi < 8; ++mi) {
        const __bf16* ap = (const __bf16*)Pb +
            (size_t)(Mbase + mi * 16 + cc) * D_DIM + quad * 8;
        #pragma unroll
        for (int kb = 0; kb < 8; ++kb)
            af[mi][kb] = *(const bf16x8*)(ap + kb * 32);
    }

    // ---- per-row threshold / label (C/D rows: quad*4 + r) ----
    float sr[8][4];
    int   tr[8][4];
    #pragma unroll
    for (int mi = 0; mi < 8; ++mi)
        #pragma unroll
        for (int r = 0; r < 4; ++r) {
            int row = Mbase + mi * 16 + quad * 4 + r;
            sr[mi][r] = s_t[row];
            tr[mi][r] = labels[row];
        }

    // frag LDS k-offsets: row&7 == cc&7, so qc depends only on (kb,quad,cc)
    int koff[8];
    #pragma unroll
    for (int kb = 0; kb < 8; ++kb) {
        int ci = kb * 4 + quad;
        koff[kb] = ((ci & 24) | ((ci ^ cc) & 7)) * 16;
    }

    int cnt[8][4] = {};

    for (int s = s0; s < s1; ++s) {
        const int p = (s - s0) & 1;
        __syncthreads();   // publishes slab s (drains its DMA); buf p^1 free

        if (s + 1 < s1) {
            const char* gbase = (const char*)Lb + (size_t)(s + 1) * (SLABN * D_DIM * 2);
            char* lbase = (char*)Bs + (size_t)(p ^ 1) * (SLABN * D_DIM * 2);
            #pragma unroll
            for (int j = 0; j < 8; ++j)
                async16(gbase + dma_off[j],
                        lbase + (size_t)(wave * 512 + j * 64) * 16);
        }

        const char* bp = (const char*)Bs + (size_t)p * (SLABN * D_DIM * 2);

        #pragma unroll
        for (int nf = 0; nf < 4; ++nf) {
            const char* brow = bp + (size_t)(nf * 16 + cc) * 512;
            f32x4 acc[8] = {};
            #pragma unroll
            for (int kb = 0; kb < 8; ++kb) {
                bf16x8 bv = *(const bf16x8*)(brow + koff[kb]);
                #pragma unroll
                for (int mi = 0; mi < 8; ++mi)
                    acc[mi] = __builtin_amdgcn_mfma_f32_16x16x32_bf16(
                        af[mi][kb], bv, acc[mi], 0, 0, 0);
            }
            int n = s * SLABN + nf * 16 + cc;
            #pragma unroll
            for (int mi = 0; mi < 8; ++mi)
                #pragma unroll
                for (int r = 0; r < 4; ++r) {
                    float sv = acc[mi][r];
                    bool beat = (n != tr[mi][r]) &&
                                (sv > sr[mi][r] ||
                                 (sv == sr[mi][r] && n < tr[mi][r]));
                    cnt[mi][r] += beat ? 1 : 0;
                }
        }
    }

    // ---- reduce over the 16 cc lanes, one atomic per (quad, mi, r) ----
    #pragma unroll
    for (int mi = 0; mi < 8; ++mi)
        #pragma unroll
        for (int r = 0; r < 4; ++r) {
            int v = cnt[mi][r];
            v += __shfl_xor(v, 1, 64);
            v += __shfl_xor(v, 2, 64);
            v += __shfl_xor(v, 4, 64);
            v += __shfl_xor(v, 8, 64);
            if (cc == 0) {
                int row = Mbase + mi * 16 + quad * 4 + r;
                atomicAdd(&counts[row], v);
            }
        }
}

// ---------------------------------------------------------------------------
// Kernel 2 (fallback, R1 path) — only if ws too small for bf16 copies.
// ---------------------------------------------------------------------------
#define FBM 128
#define FBN 128
#define FBK 32
#define KPAD 40

__global__ __launch_bounds__(256)
void count_kernel_slow(const float* __restrict__ P,
                       const float* __restrict__ Lab,
                       const int*   __restrict__ labels,
                       const float* __restrict__ s_t,
                       int* __restrict__ counts) {
    __shared__ __align__(16) __bf16 As[FBM][KPAD];
    __shared__ __align__(16) __bf16 Bs[FBN][KPAD];

    const int Nbase = blockIdx.x * FBN;
    const int Mbase = blockIdx.y * FBM;
    const int tid  = threadIdx.x;
    const int lane = tid & 63;
    const int wave = tid >> 6;
    const int wm = wave >> 1;
    const int wn = wave & 1;
    const int quad = lane >> 4;
    const int c    = lane & 15;

    const int srow  = tid >> 1;
    const int skoff = (tid & 1) * 16;
    const int brow_g = min(Nbase + srow, L_LABELS - 1);

    f32x4 acc[4][4] = {};

    for (int Kb = 0; Kb < D_DIM; Kb += FBK) {
        const float* gA = P   + (size_t)(Mbase + srow) * D_DIM + Kb + skoff;
        const float* gB = Lab + (size_t)brow_g        * D_DIM + Kb + skoff;
        #pragma unroll
        for (int i = 0; i < 4; ++i) {
            float4 va = *(const float4*)(gA + i * 4);
            float4 vb = *(const float4*)(gB + i * 4);
            *(bf16x4*)&As[srow][skoff + i * 4] =
                (bf16x4){(__bf16)va.x, (__bf16)va.y, (__bf16)va.z, (__bf16)va.w};
            *(bf16x4*)&Bs[srow][skoff + i * 4] =
                (bf16x4){(__bf16)vb.x, (__bf16)vb.y, (__bf16)vb.z, (__bf16)vb.w};
        }
        __syncthreads();

        bf16x8 afr[4], bfr[4];
        #pragma unroll
        for (int mi = 0; mi < 4; ++mi)
            afr[mi] = *(const bf16x8*)&As[wm * 64 + mi * 16 + c][quad * 8];
        #pragma unroll
        for (int ni = 0; ni < 4; ++ni)
            bfr[ni] = *(const bf16x8*)&Bs[wn * 64 + ni * 16 + c][quad * 8];

        #pragma unroll
        for (int mi = 0; mi < 4; ++mi)
            #pragma unroll
            for (int ni = 0; ni < 4; ++ni)
                acc[mi][ni] = __builtin_amdgcn_mfma_f32_16x16x32_bf16(
                    afr[mi], bfr[ni], acc[mi][ni], 0, 0, 0);
        __syncthreads();
    }

    #pragma unroll
    for (int mi = 0; mi < 4; ++mi) {
        int rowb = Mbase + wm * 64 + mi * 16 + quad * 4;
        #pragma unroll
        for (int r = 0; r < 4; ++r) {
            int   row = rowb + r;
            float st  = s_t[row];
            int   t   = labels[row];
            int   cnt = 0;
            #pragma unroll
            for (int ni = 0; ni < 4; ++ni) {
                int   n = Nbase + wn * 64 + ni * 16 + c;
                float s = acc[mi][ni][r];
                bool beat = (n < L_LABELS) && (n != t) &&
                            (s > st || (s == st && n < t));
                cnt += beat ? 1 : 0;
            }
            cnt += __shfl_xor(cnt, 1, 64);
            cnt += __shfl_xor(cnt, 2, 64);
            cnt += __shfl_xor(cnt, 4, 64);
            cnt += __shfl_xor(cnt, 8, 64);
            if (c == 0 && cnt) atomicAdd(&counts[row], cnt);
        }
    }
}

// ---------------------------------------------------------------------------
// Kernel 3: accuracy = mean(adjusted_counts[b] < TOPK). Fast path pads with
// zero rows -> each row got PADROWS phantom beats iff s_t < 0.
// ---------------------------------------------------------------------------
__global__ void finalize_kernel(const int* __restrict__ counts,
                                const float* __restrict__ s_t,
                                float* __restrict__ out,
                                int pad_correct) {
    __shared__ int sdata[4];
    int tid = threadIdx.x;
    int local = 0;
    for (int i = tid; i < B_ROWS; i += 256) {
        int c = counts[i];
        if (pad_correct && s_t[i] < 0.0f) c -= PADROWS;
        local += (c < TOPK) ? 1 : 0;
    }
    #pragma unroll
    for (int m = 1; m < 64; m <<= 1) local += __shfl_xor(local, m, 64);
    if ((tid & 63) == 0) sdata[tid >> 6] = local;
    __syncthreads();
    if (tid == 0)
        out[0] = (float)(sdata[0] + sdata[1] + sdata[2] + sdata[3]) /
                 (float)B_ROWS;
}

extern "C" void kernel_launch(void* const* d_in, const int* in_sizes, int n_in,
                              void* d_out, int out_size, void* d_ws, size_t ws_size,
                              hipStream_t stream) {
    const float* P      = (const float*)d_in[0];
    const float* Lab    = (const float*)d_in[1];
    const int*   labels = (const int*)d_in[2];
    float* out = (float*)d_out;

    float* s_t    = (float*)d_ws;
    int*   counts = (int*)((char*)d_ws + 16384);

    prep_kernel<<<dim3(B_ROWS / 4), 256, 0, stream>>>(P, Lab, labels, s_t, counts);

    const size_t pb_off = 32768;
    const size_t lb_off = pb_off + (size_t)B_ROWS * D_DIM * 2;  // 2 MB
    const size_t need   = lb_off + (size_t)L_PAD * D_DIM * 2;   // ~51 MB

    int fast = (ws_size >= need) ? 1 : 0;
    if (fast) {
        __hip_bfloat16* Pb = (__hip_bfloat16*)((char*)d_ws + pb_off);
        __hip_bfloat16* Lb = (__hip_bfloat16*)((char*)d_ws + lb_off);
        convertP_kernel<<<dim3((B_ROWS * D_DIM) / 2048), 256, 0, stream>>>(P, Pb);
        convertL_kernel<<<dim3(((size_t)L_PAD * D_DIM) / 2048), 256, 0, stream>>>(Lab, Lb);
        // grid: 32 label-groups (x: group g -> XCD g%8) x 8 M-tiles of 512
        count_kernel_v6<<<dim3(NGROUP, B_ROWS / 512), 256, 0, stream>>>(
            Pb, Lb, labels, s_t, counts);
    } else {
        dim3 grid((L_LABELS + FBN - 1) / FBN, B_ROWS / FBM);
        count_kernel_slow<<<grid, 256, 0, stream>>>(P, Lab, labels, s_t, counts);
    }

    finalize_kernel<<<1, 256, 0, stream>>>(counts, s_t, out, fast);
}

// Round 7
// 546.366 us; speedup vs baseline: 1.6947x; 1.6947x over previous
//
#include <hip/hip_runtime.h>
#include <hip/hip_bf16.h>

#define B_ROWS   4096
#define L_LABELS 100000
#define L_PAD    100096   // 782 * 128, padded with zero rows
#define PADROWS  96
#define D_DIM    256
#define TOPK     5
#define SLABN    128      // labels per slab
#define NSLAB    782      // L_PAD / SLABN
#define NGROUP   8        // label groups (grid.x) -> XCD

typedef __bf16 bf16x8 __attribute__((ext_vector_type(8)));
typedef __bf16 bf16x4 __attribute__((ext_vector_type(4)));
typedef float  f32x4  __attribute__((ext_vector_type(4)));

__device__ __forceinline__ void async16(const void* g, void* l) {
    __builtin_amdgcn_global_load_lds(
        (const __attribute__((address_space(1))) unsigned int*)g,
        (__attribute__((address_space(3))) unsigned int*)l,
        16, 0, 0);
}

// ---------------------------------------------------------------------------
// fp32 -> bf16 converters
// ---------------------------------------------------------------------------
__global__ void convertP_kernel(const float* __restrict__ src,
                                __hip_bfloat16* __restrict__ dst) {
    size_t i = ((size_t)blockIdx.x * blockDim.x + threadIdx.x) * 8;
    float4 a = *(const float4*)(src + i);
    float4 b = *(const float4*)(src + i + 4);
    bf16x8 v = {(__bf16)a.x, (__bf16)a.y, (__bf16)a.z, (__bf16)a.w,
                (__bf16)b.x, (__bf16)b.y, (__bf16)b.z, (__bf16)b.w};
    *(bf16x8*)((__bf16*)dst + i) = v;
}

__global__ void convertL_kernel(const float* __restrict__ src,
                                __hip_bfloat16* __restrict__ dst) {
    size_t i = ((size_t)blockIdx.x * blockDim.x + threadIdx.x) * 8;
    bf16x8 v;
    if (i < (size_t)L_LABELS * D_DIM) {
        float4 a = *(const float4*)(src + i);
        float4 b = *(const float4*)(src + i + 4);
        v = (bf16x8){(__bf16)a.x, (__bf16)a.y, (__bf16)a.z, (__bf16)a.w,
                     (__bf16)b.x, (__bf16)b.y, (__bf16)b.z, (__bf16)b.w};
    } else {
        v = (bf16x8){(__bf16)0.f, (__bf16)0.f, (__bf16)0.f, (__bf16)0.f,
                     (__bf16)0.f, (__bf16)0.f, (__bf16)0.f, (__bf16)0.f};
    }
    *(bf16x8*)((__bf16*)dst + i) = v;
}

// ---------------------------------------------------------------------------
// Kernel 1: per-row threshold s_t (bf16-rounded inputs) + zero counters.
// ---------------------------------------------------------------------------
__global__ void prep_kernel(const float* __restrict__ P,
                            const float* __restrict__ Lab,
                            const int*   __restrict__ labels,
                            float* __restrict__ s_t,
                            int*   __restrict__ counts) {
    int gwave = (blockIdx.x * blockDim.x + threadIdx.x) >> 6;
    int lane  = threadIdx.x & 63;
    if (gwave >= B_ROWS) return;
    int t = labels[gwave];
    const float4* p4 = (const float4*)(P + (size_t)gwave * D_DIM);
    const float4* l4 = (const float4*)(Lab + (size_t)t * D_DIM);
    float4 a = p4[lane];
    float4 b = l4[lane];
    float sum = 0.f;
    sum += (float)(__bf16)a.x * (float)(__bf16)b.x;
    sum += (float)(__bf16)a.y * (float)(__bf16)b.y;
    sum += (float)(__bf16)a.z * (float)(__bf16)b.z;
    sum += (float)(__bf16)a.w * (float)(__bf16)b.w;
    #pragma unroll
    for (int m = 1; m < 64; m <<= 1) sum += __shfl_xor(sum, m, 64);
    if (lane == 0) {
        s_t[gwave]    = sum;
        counts[gwave] = 0;
    }
}

// ---------------------------------------------------------------------------
// Kernel 2 (v7): 8-wave (2/SIMD) A-stationary + DMA-dbuf B streaming.
// Block = 512 thr = 8 waves (wm 0..1 x wn 0..3). Each wave: af[4][8] =
// 128 VGPR stationary (64 A-rows x K=256). B: 128-label slabs (64 KB)
// double-buffered via global_load_lds (no staging VGPRs). One barrier per
// slab; its vmcnt drain waits on a DMA issued a full slab (~2500 cyc) ago.
// Within-wave nf-pipelining: prefetch next 16-label B-frags during MFMAs.
// Source-side XOR chunk swizzle as in v6 (validated: ~1 cyc/read conflicts).
// Pad rows contribute +0.0f; corrected in finalize.
// ---------------------------------------------------------------------------
__global__ __launch_bounds__(512, 2)
void count_kernel_v7(const __hip_bfloat16* __restrict__ Pb,
                     const __hip_bfloat16* __restrict__ Lb,
                     const int*   __restrict__ labels,
                     const float* __restrict__ s_t,
                     int* __restrict__ counts) {
    __shared__ __align__(16) __bf16 Bs[2 * SLABN * D_DIM];   // 2 x 64 KB

    const int group = blockIdx.x;            // 0..7 -> XCD
    const int tid   = threadIdx.x;
    const int wave  = tid >> 6;              // 0..7
    const int lane  = tid & 63;
    const int wm    = wave >> 2;             // 0..1
    const int wn    = wave & 3;              // 0..3
    const int quad  = lane >> 4;             // 0..3
    const int cc    = lane & 15;             // 0..15
    const int Mbase = blockIdx.y * 128 + wm * 64;

    const int s0 = (group * NSLAB) / NGROUP;
    const int s1 = ((group + 1) * NSLAB) / NGROUP;

    // per-thread DMA source offsets (bytes within a 64 KB slab): 8 instr
    int dma_off[8];
    #pragma unroll
    for (int j = 0; j < 8; ++j) {
        int c   = j * 512 + tid;             // chunk 0..4095
        int row = c >> 5;                    // label row 0..127
        int qc  = c & 31;
        int gc  = (qc & 24) | ((qc ^ row) & 7);
        dma_off[j] = row * 512 + gc * 16;
    }

    // ---- issue DMA for first slab into buffer 0 ----
    {
        const char* gbase = (const char*)Lb + (size_t)s0 * (SLABN * D_DIM * 2);
        #pragma unroll
        for (int j = 0; j < 8; ++j)
            async16(gbase + dma_off[j],
                    (char*)Bs + (size_t)(j * 512 + wave * 64) * 16);
    }

    // ---- stationary A fragments: 64 rows x K=256 (128 VGPR) ----
    bf16x8 af[4][8];
    #pragma unroll
    for (int mi = 0; mi < 4; ++mi) {
        const __bf16* ap = (const __bf16*)Pb +
            (size_t)(Mbase + mi * 16 + cc) * D_DIM + quad * 8;
        #pragma unroll
        for (int kb = 0; kb < 8; ++kb)
            af[mi][kb] = *(const bf16x8*)(ap + kb * 32);
    }

    // ---- per-row threshold / label (C/D rows: quad*4 + r) ----
    float sr[4][4];
    int   tr[4][4];
    #pragma unroll
    for (int mi = 0; mi < 4; ++mi)
        #pragma unroll
        for (int r = 0; r < 4; ++r) {
            int row = Mbase + mi * 16 + quad * 4 + r;
            sr[mi][r] = s_t[row];
            tr[mi][r] = labels[row];
        }

    // frag LDS k-offsets (row&7 == cc&7 for all our reads)
    int koff[8];
    #pragma unroll
    for (int kb = 0; kb < 8; ++kb) {
        int ci = kb * 4 + quad;
        koff[kb] = ((ci & 24) | ((ci ^ cc) & 7)) * 16;
    }

    int cnt[4][4] = {};

    for (int s = s0; s < s1; ++s) {
        const int p = (s - s0) & 1;
        __syncthreads();   // publishes slab s (its DMA issued a slab ago)

        if (s + 1 < s1) {
            const char* gbase = (const char*)Lb + (size_t)(s + 1) * (SLABN * D_DIM * 2);
            char* lbase = (char*)Bs + (size_t)(p ^ 1) * (SLABN * D_DIM * 2);
            #pragma unroll
            for (int j = 0; j < 8; ++j)
                async16(gbase + dma_off[j],
                        lbase + (size_t)(j * 512 + wave * 64) * 16);
        }

        const char* bp = (const char*)Bs + (size_t)p * (SLABN * D_DIM * 2);
        // wave's label rows this slab: wn*32 + nf*16 + cc, nf in {0,1}
        const char* brow0 = bp + (size_t)(wn * 32 + cc) * 512;

        // preload nf=0 frags
        bf16x8 bv[8], bnext[8];
        #pragma unroll
        for (int kb = 0; kb < 8; ++kb)
            bv[kb] = *(const bf16x8*)(brow0 + koff[kb]);

        #pragma unroll
        for (int nf = 0; nf < 2; ++nf) {
            // prefetch nf=1 frags while nf=0 computes
            if (nf == 0) {
                const char* brow1 = brow0 + 16 * 512;
                #pragma unroll
                for (int kb = 0; kb < 8; ++kb)
                    bnext[kb] = *(const bf16x8*)(brow1 + koff[kb]);
            }
            f32x4 acc[4] = {};
            #pragma unroll
            for (int kb = 0; kb < 8; ++kb) {
                #pragma unroll
                for (int mi = 0; mi < 4; ++mi)
                    acc[mi] = __builtin_amdgcn_mfma_f32_16x16x32_bf16(
                        af[mi][kb], bv[kb], acc[mi], 0, 0, 0);
            }
            int n = s * SLABN + wn * 32 + nf * 16 + cc;
            #pragma unroll
            for (int mi = 0; mi < 4; ++mi)
                #pragma unroll
                for (int r = 0; r < 4; ++r) {
                    float sv = acc[mi][r];
                    bool beat = (n != tr[mi][r]) &&
                                (sv > sr[mi][r] ||
                                 (sv == sr[mi][r] && n < tr[mi][r]));
                    cnt[mi][r] += beat ? 1 : 0;
                }
            #pragma unroll
            for (int kb = 0; kb < 8; ++kb) bv[kb] = bnext[kb];
        }
    }

    // ---- reduce over the 16 cc lanes, one atomic per (quad, mi, r) ----
    #pragma unroll
    for (int mi = 0; mi < 4; ++mi)
        #pragma unroll
        for (int r = 0; r < 4; ++r) {
            int v = cnt[mi][r];
            v += __shfl_xor(v, 1, 64);
            v += __shfl_xor(v, 2, 64);
            v += __shfl_xor(v, 4, 64);
            v += __shfl_xor(v, 8, 64);
            if (cc == 0) {
                int row = Mbase + mi * 16 + quad * 4 + r;
                atomicAdd(&counts[row], v);
            }
        }
}

// ---------------------------------------------------------------------------
// Kernel 2 (fallback, R1 path) — only if ws too small for bf16 copies.
// ---------------------------------------------------------------------------
#define FBM 128
#define FBN 128
#define FBK 32
#define KPAD 40

__global__ __launch_bounds__(256)
void count_kernel_slow(const float* __restrict__ P,
                       const float* __restrict__ Lab,
                       const int*   __restrict__ labels,
                       const float* __restrict__ s_t,
                       int* __restrict__ counts) {
    __shared__ __align__(16) __bf16 As[FBM][KPAD];
    __shared__ __align__(16) __bf16 Bs[FBN][KPAD];

    const int Nbase = blockIdx.x * FBN;
    const int Mbase = blockIdx.y * FBM;
    const int tid  = threadIdx.x;
    const int lane = tid & 63;
    const int wave = tid >> 6;
    const int wm = wave >> 1;
    const int wn = wave & 1;
    const int quad = lane >> 4;
    const int c    = lane & 15;

    const int srow  = tid >> 1;
    const int skoff = (tid & 1) * 16;
    const int brow_g = min(Nbase + srow, L_LABELS - 1);

    f32x4 acc[4][4] = {};

    for (int Kb = 0; Kb < D_DIM; Kb += FBK) {
        const float* gA = P   + (size_t)(Mbase + srow) * D_DIM + Kb + skoff;
        const float* gB = Lab + (size_t)brow_g        * D_DIM + Kb + skoff;
        #pragma unroll
        for (int i = 0; i < 4; ++i) {
            float4 va = *(const float4*)(gA + i * 4);
            float4 vb = *(const float4*)(gB + i * 4);
            *(bf16x4*)&As[srow][skoff + i * 4] =
                (bf16x4){(__bf16)va.x, (__bf16)va.y, (__bf16)va.z, (__bf16)va.w};
            *(bf16x4*)&Bs[srow][skoff + i * 4] =
                (bf16x4){(__bf16)vb.x, (__bf16)vb.y, (__bf16)vb.z, (__bf16)vb.w};
        }
        __syncthreads();

        bf16x8 afr[4], bfr[4];
        #pragma unroll
        for (int mi = 0; mi < 4; ++mi)
            afr[mi] = *(const bf16x8*)&As[wm * 64 + mi * 16 + c][quad * 8];
        #pragma unroll
        for (int ni = 0; ni < 4; ++ni)
            bfr[ni] = *(const bf16x8*)&Bs[wn * 64 + ni * 16 + c][quad * 8];

        #pragma unroll
        for (int mi = 0; mi < 4; ++mi)
            #pragma unroll
            for (int ni = 0; ni < 4; ++ni)
                acc[mi][ni] = __builtin_amdgcn_mfma_f32_16x16x32_bf16(
                    afr[mi], bfr[ni], acc[mi][ni], 0, 0, 0);
        __syncthreads();
    }

    #pragma unroll
    for (int mi = 0; mi < 4; ++mi) {
        int rowb = Mbase + wm * 64 + mi * 16 + quad * 4;
        #pragma unroll
        for (int r = 0; r < 4; ++r) {
            int   row = rowb + r;
            float st  = s_t[row];
            int   t   = labels[row];
            int   cnt = 0;
            #pragma unroll
            for (int ni = 0; ni < 4; ++ni) {
                int   n = Nbase + wn * 64 + ni * 16 + c;
                float s = acc[mi][ni][r];
                bool beat = (n < L_LABELS) && (n != t) &&
                            (s > st || (s == st && n < t));
                cnt += beat ? 1 : 0;
            }
            cnt += __shfl_xor(cnt, 1, 64);
            cnt += __shfl_xor(cnt, 2, 64);
            cnt += __shfl_xor(cnt, 4, 64);
            cnt += __shfl_xor(cnt, 8, 64);
            if (c == 0 && cnt) atomicAdd(&counts[row], cnt);
        }
    }
}

// ---------------------------------------------------------------------------
// Kernel 3: accuracy = mean(adjusted_counts[b] < TOPK). Fast path pads with
// zero rows -> each row got PADROWS phantom beats iff s_t < 0.
// ---------------------------------------------------------------------------
__global__ void finalize_kernel(const int* __restrict__ counts,
                                const float* __restrict__ s_t,
                                float* __restrict__ out,
                                int pad_correct) {
    __shared__ int sdata[4];
    int tid = threadIdx.x;
    int local = 0;
    for (int i = tid; i < B_ROWS; i += 256) {
        int c = counts[i];
        if (pad_correct && s_t[i] < 0.0f) c -= PADROWS;
        local += (c < TOPK) ? 1 : 0;
    }
    #pragma unroll
    for (int m = 1; m < 64; m <<= 1) local += __shfl_xor(local, m, 64);
    if ((tid & 63) == 0) sdata[tid >> 6] = local;
    __syncthreads();
    if (tid == 0)
        out[0] = (float)(sdata[0] + sdata[1] + sdata[2] + sdata[3]) /
                 (float)B_ROWS;
}

extern "C" void kernel_launch(void* const* d_in, const int* in_sizes, int n_in,
                              void* d_out, int out_size, void* d_ws, size_t ws_size,
                              hipStream_t stream) {
    const float* P      = (const float*)d_in[0];
    const float* Lab    = (const float*)d_in[1];
    const int*   labels = (const int*)d_in[2];
    float* out = (float*)d_out;

    float* s_t    = (float*)d_ws;
    int*   counts = (int*)((char*)d_ws + 16384);

    prep_kernel<<<dim3(B_ROWS / 4), 256, 0, stream>>>(P, Lab, labels, s_t, counts);

    const size_t pb_off = 32768;
    const size_t lb_off = pb_off + (size_t)B_ROWS * D_DIM * 2;  // 2 MB
    const size_t need   = lb_off + (size_t)L_PAD * D_DIM * 2;   // ~51 MB

    int fast = (ws_size >= need) ? 1 : 0;
    if (fast) {
        __hip_bfloat16* Pb = (__hip_bfloat16*)((char*)d_ws + pb_off);
        __hip_bfloat16* Lb = (__hip_bfloat16*)((char*)d_ws + lb_off);
        convertP_kernel<<<dim3((B_ROWS * D_DIM) / 2048), 256, 0, stream>>>(P, Pb);
        convertL_kernel<<<dim3(((size_t)L_PAD * D_DIM) / 2048), 256, 0, stream>>>(Lab, Lb);
        // grid: 8 label-groups (XCD round-robin) x 32 M-tiles of 128
        count_kernel_v7<<<dim3(NGROUP, B_ROWS / 128), 512, 0, stream>>>(
            Pb, Lb, labels, s_t, counts);
    } else {
        dim3 grid((L_LABELS + FBN - 1) / FBN, B_ROWS / FBM);
        count_kernel_slow<<<grid, 256, 0, stream>>>(P, Lab, labels, s_t, counts);
    }

    finalize_kernel<<<1, 256, 0, stream>>>(counts, s_t, out, fast);
}

// Round 8
// 525.652 us; speedup vs baseline: 1.7615x; 1.0394x over previous
//
#include <hip/hip_runtime.h>
#include <hip/hip_bf16.h>

#define B_ROWS   4096
#define L_LABELS 100000
#define L_PAD    100032   // 6252*16: slack rows so depth-1 prefetch stays in-bounds
#define D_DIM    256
#define TOPK     5
#define NSTEP    6250     // 100000 / 16 exact -> no pad corrections
#define NSTRIP   32       // label strips; strip = blockIdx.x

typedef __bf16 bf16x8 __attribute__((ext_vector_type(8)));
typedef __bf16 bf16x4 __attribute__((ext_vector_type(4)));
typedef float  f32x4  __attribute__((ext_vector_type(4)));

// ---------------------------------------------------------------------------
// fp32 -> bf16 converters
// ---------------------------------------------------------------------------
__global__ void convertP_kernel(const float* __restrict__ src,
                                __hip_bfloat16* __restrict__ dst) {
    size_t i = ((size_t)blockIdx.x * blockDim.x + threadIdx.x) * 8;
    float4 a = *(const float4*)(src + i);
    float4 b = *(const float4*)(src + i + 4);
    bf16x8 v = {(__bf16)a.x, (__bf16)a.y, (__bf16)a.z, (__bf16)a.w,
                (__bf16)b.x, (__bf16)b.y, (__bf16)b.z, (__bf16)b.w};
    *(bf16x8*)((__bf16*)dst + i) = v;
}

__global__ void convertL_kernel(const float* __restrict__ src,
                                __hip_bfloat16* __restrict__ dst) {
    size_t i = ((size_t)blockIdx.x * blockDim.x + threadIdx.x) * 8;
    bf16x8 v;
    if (i < (size_t)L_LABELS * D_DIM) {
        float4 a = *(const float4*)(src + i);
        float4 b = *(const float4*)(src + i + 4);
        v = (bf16x8){(__bf16)a.x, (__bf16)a.y, (__bf16)a.z, (__bf16)a.w,
                     (__bf16)b.x, (__bf16)b.y, (__bf16)b.z, (__bf16)b.w};
    } else {
        v = (bf16x8){(__bf16)0.f, (__bf16)0.f, (__bf16)0.f, (__bf16)0.f,
                     (__bf16)0.f, (__bf16)0.f, (__bf16)0.f, (__bf16)0.f};
    }
    *(bf16x8*)((__bf16*)dst + i) = v;
}

// ---------------------------------------------------------------------------
// Kernel 1: per-row threshold s_t (bf16-rounded inputs) + zero counters.
// ---------------------------------------------------------------------------
__global__ void prep_kernel(const float* __restrict__ P,
                            const float* __restrict__ Lab,
                            const int*   __restrict__ labels,
                            float* __restrict__ s_t,
                            int*   __restrict__ counts) {
    int gwave = (blockIdx.x * blockDim.x + threadIdx.x) >> 6;
    int lane  = threadIdx.x & 63;
    if (gwave >= B_ROWS) return;
    int t = labels[gwave];
    const float4* p4 = (const float4*)(P + (size_t)gwave * D_DIM);
    const float4* l4 = (const float4*)(Lab + (size_t)t * D_DIM);
    float4 a = p4[lane];
    float4 b = l4[lane];
    float sum = 0.f;
    sum += (float)(__bf16)a.x * (float)(__bf16)b.x;
    sum += (float)(__bf16)a.y * (float)(__bf16)b.y;
    sum += (float)(__bf16)a.z * (float)(__bf16)b.z;
    sum += (float)(__bf16)a.w * (float)(__bf16)b.w;
    #pragma unroll
    for (int m = 1; m < 64; m <<= 1) sum += __shfl_xor(sum, m, 64);
    if (lane == 0) {
        s_t[gwave]    = sum;
        counts[gwave] = 0;
    }
}

// ---------------------------------------------------------------------------
// Kernel 2 (v8): barrier-free, LDS-free streaming count GEMM with
// block-wide B sharing.
// Block 256 thr = 4 waves. ALL 4 waves read the SAME label strip
// (strip = blockIdx.x); wave index selects the 64-row M slice, so the block
// covers 256 M-rows x one strip and each 8 KB B-step is fetched from L2
// once into L1 and broadcast to 4 waves (L2 demand ~13 B/cyc/CU, 4x under
// ceiling). Per wave: 64 stationary A rows in regs (af[4][8] = 128 VGPR) x
// full K=256; B streamed 16 labels/step directly global->reg in native
// 16x16x32 B-operand layout (lane (quad,cc) reads Lb[n=cc][kb*32+quad*8]).
// Depth-1 rolling prefetch hides L2 latency. No __syncthreads anywhere;
// 2 independent blocks/CU give the m114-style cross-block overlap.
// Same-strip blocks are 32 apart in linear dispatch -> same XCD L2.
// ---------------------------------------------------------------------------
__global__ __launch_bounds__(256, 2)
void count_kernel_v8(const __hip_bfloat16* __restrict__ Pb,
                     const __hip_bfloat16* __restrict__ Lb,
                     const int*   __restrict__ labels,
                     const float* __restrict__ s_t,
                     int* __restrict__ counts) {
    const int tid  = threadIdx.x;
    const int wave = tid >> 6;           // 0..3 -> M slice
    const int lane = tid & 63;
    const int quad = lane >> 4;          // 0..3
    const int cc   = lane & 15;          // 0..15

    const int Mbase = blockIdx.y * 256 + wave * 64;
    const int sigma = blockIdx.x;        // 0..31 strip id
    const int s0 = (sigma * NSTEP) >> 5;
    const int s1 = ((sigma + 1) * NSTEP) >> 5;

    // ---- stationary A fragments: 64 rows x K=256 ----
    bf16x8 af[4][8];
    #pragma unroll
    for (int mi = 0; mi < 4; ++mi) {
        const __bf16* ap = (const __bf16*)Pb +
            (size_t)(Mbase + mi * 16 + cc) * D_DIM + quad * 8;
        #pragma unroll
        for (int kb = 0; kb < 8; ++kb)
            af[mi][kb] = *(const bf16x8*)(ap + kb * 32);
    }

    // ---- per-row threshold / label ----
    float sr[4][4];
    int   tr[4][4];
    #pragma unroll
    for (int mi = 0; mi < 4; ++mi)
        #pragma unroll
        for (int r = 0; r < 4; ++r) {
            int row = Mbase + mi * 16 + quad * 4 + r;
            sr[mi][r] = s_t[row];
            tr[mi][r] = labels[row];
        }

    int cnt[4][4] = {};

    // per-lane B gather pointer: row = s*16 + cc, k-bytes = quad*16 (+kb*64)
    const char* pf = (const char*)Lb +
        (size_t)(s0 * 16 + cc) * (D_DIM * 2) + quad * 16;

    // prime step s0
    uint4 breg[8];
    #pragma unroll
    for (int kb = 0; kb < 8; ++kb)
        breg[kb] = *(const uint4*)(pf + kb * 64);
    pf += 16 * (D_DIM * 2);

    for (int s = s0; s < s1; ++s) {
        f32x4 acc[4] = {};
        #pragma unroll
        for (int kb = 0; kb < 8; ++kb) {
            bf16x8 bv = *(const bf16x8*)&breg[kb];
            #pragma unroll
            for (int mi = 0; mi < 4; ++mi)
                acc[mi] = __builtin_amdgcn_mfma_f32_16x16x32_bf16(
                    af[mi][kb], bv, acc[mi], 0, 0, 0);
            // rolling depth-1 prefetch of step s+1 (rows stay < L_PAD)
            breg[kb] = *(const uint4*)(pf + kb * 64);
        }
        pf += 16 * (D_DIM * 2);

        int n = s * 16 + cc;
        #pragma unroll
        for (int mi = 0; mi < 4; ++mi)
            #pragma unroll
            for (int r = 0; r < 4; ++r) {
                float sv = acc[mi][r];
                bool beat = (n != tr[mi][r]) &&
                            (sv > sr[mi][r] ||
                             (sv == sr[mi][r] && n < tr[mi][r]));
                cnt[mi][r] += beat ? 1 : 0;
            }
    }

    // ---- reduce over the 16 cc lanes, one atomic per (quad, mi, r) ----
    #pragma unroll
    for (int mi = 0; mi < 4; ++mi)
        #pragma unroll
        for (int r = 0; r < 4; ++r) {
            int v = cnt[mi][r];
            v += __shfl_xor(v, 1, 64);
            v += __shfl_xor(v, 2, 64);
            v += __shfl_xor(v, 4, 64);
            v += __shfl_xor(v, 8, 64);
            if (cc == 0) {
                int row = Mbase + mi * 16 + quad * 4 + r;
                atomicAdd(&counts[row], v);
            }
        }
}

// ---------------------------------------------------------------------------
// Kernel 2 (fallback, R1 path) — only if ws too small for bf16 copies.
// ---------------------------------------------------------------------------
#define FBM 128
#define FBN 128
#define FBK 32
#define KPAD 40

__global__ __launch_bounds__(256)
void count_kernel_slow(const float* __restrict__ P,
                       const float* __restrict__ Lab,
                       const int*   __restrict__ labels,
                       const float* __restrict__ s_t,
                       int* __restrict__ counts) {
    __shared__ __align__(16) __bf16 As[FBM][KPAD];
    __shared__ __align__(16) __bf16 Bs[FBN][KPAD];

    const int Nbase = blockIdx.x * FBN;
    const int Mbase = blockIdx.y * FBM;
    const int tid  = threadIdx.x;
    const int lane = tid & 63;
    const int wave = tid >> 6;
    const int wm = wave >> 1;
    const int wn = wave & 1;
    const int quad = lane >> 4;
    const int c    = lane & 15;

    const int srow  = tid >> 1;
    const int skoff = (tid & 1) * 16;
    const int brow_g = min(Nbase + srow, L_LABELS - 1);

    f32x4 acc[4][4] = {};

    for (int Kb = 0; Kb < D_DIM; Kb += FBK) {
        const float* gA = P   + (size_t)(Mbase + srow) * D_DIM + Kb + skoff;
        const float* gB = Lab + (size_t)brow_g        * D_DIM + Kb + skoff;
        #pragma unroll
        for (int i = 0; i < 4; ++i) {
            float4 va = *(const float4*)(gA + i * 4);
            float4 vb = *(const float4*)(gB + i * 4);
            *(bf16x4*)&As[srow][skoff + i * 4] =
                (bf16x4){(__bf16)va.x, (__bf16)va.y, (__bf16)va.z, (__bf16)va.w};
            *(bf16x4*)&Bs[srow][skoff + i * 4] =
                (bf16x4){(__bf16)vb.x, (__bf16)vb.y, (__bf16)vb.z, (__bf16)vb.w};
        }
        __syncthreads();

        bf16x8 afr[4], bfr[4];
        #pragma unroll
        for (int mi = 0; mi < 4; ++mi)
            afr[mi] = *(const bf16x8*)&As[wm * 64 + mi * 16 + c][quad * 8];
        #pragma unroll
        for (int ni = 0; ni < 4; ++ni)
            bfr[ni] = *(const bf16x8*)&Bs[wn * 64 + ni * 16 + c][quad * 8];

        #pragma unroll
        for (int mi = 0; mi < 4; ++mi)
            #pragma unroll
            for (int ni = 0; ni < 4; ++ni)
                acc[mi][ni] = __builtin_amdgcn_mfma_f32_16x16x32_bf16(
                    afr[mi], bfr[ni], acc[mi][ni], 0, 0, 0);
        __syncthreads();
    }

    #pragma unroll
    for (int mi = 0; mi < 4; ++mi) {
        int rowb = Mbase + wm * 64 + mi * 16 + quad * 4;
        #pragma unroll
        for (int r = 0; r < 4; ++r) {
            int   row = rowb + r;
            float st  = s_t[row];
            int   t   = labels[row];
            int   cnt = 0;
            #pragma unroll
            for (int ni = 0; ni < 4; ++ni) {
                int   n = Nbase + wn * 64 + ni * 16 + c;
                float s = acc[mi][ni][r];
                bool beat = (n < L_LABELS) && (n != t) &&
                            (s > st || (s == st && n < t));
                cnt += beat ? 1 : 0;
            }
            cnt += __shfl_xor(cnt, 1, 64);
            cnt += __shfl_xor(cnt, 2, 64);
            cnt += __shfl_xor(cnt, 4, 64);
            cnt += __shfl_xor(cnt, 8, 64);
            if (c == 0 && cnt) atomicAdd(&counts[row], cnt);
        }
    }
}

// ---------------------------------------------------------------------------
// Kernel 3: accuracy = mean(counts[b] < TOPK)
// ---------------------------------------------------------------------------
__global__ void finalize_kernel(const int* __restrict__ counts,
                                float* __restrict__ out) {
    __shared__ int sdata[4];
    int tid = threadIdx.x;
    int local = 0;
    for (int i = tid; i < B_ROWS; i += 256)
        local += (counts[i] < TOPK) ? 1 : 0;
    #pragma unroll
    for (int m = 1; m < 64; m <<= 1) local += __shfl_xor(local, m, 64);
    if ((tid & 63) == 0) sdata[tid >> 6] = local;
    __syncthreads();
    if (tid == 0)
        out[0] = (float)(sdata[0] + sdata[1] + sdata[2] + sdata[3]) /
                 (float)B_ROWS;
}

extern "C" void kernel_launch(void* const* d_in, const int* in_sizes, int n_in,
                              void* d_out, int out_size, void* d_ws, size_t ws_size,
                              hipStream_t stream) {
    const float* P      = (const float*)d_in[0];
    const float* Lab    = (const float*)d_in[1];
    const int*   labels = (const int*)d_in[2];
    float* out = (float*)d_out;

    float* s_t    = (float*)d_ws;
    int*   counts = (int*)((char*)d_ws + 16384);

    prep_kernel<<<dim3(B_ROWS / 4), 256, 0, stream>>>(P, Lab, labels, s_t, counts);

    const size_t pb_off = 32768;
    const size_t lb_off = pb_off + (size_t)B_ROWS * D_DIM * 2;  // 2 MB
    const size_t need   = lb_off + (size_t)L_PAD * D_DIM * 2;   // ~51 MB

    if (ws_size >= need) {
        __hip_bfloat16* Pb = (__hip_bfloat16*)((char*)d_ws + pb_off);
        __hip_bfloat16* Lb = (__hip_bfloat16*)((char*)d_ws + lb_off);
        convertP_kernel<<<dim3((B_ROWS * D_DIM) / 2048), 256, 0, stream>>>(P, Pb);
        convertL_kernel<<<dim3(((size_t)L_PAD * D_DIM) / 2048), 256, 0, stream>>>(Lab, Lb);
        // grid: 32 strips x 16 M-blocks of 256 rows = 512 blocks (2/CU).
        // Same-strip blocks are 32 apart linearly -> same XCD -> L2-local B.
        count_kernel_v8<<<dim3(NSTRIP, B_ROWS / 256), 256, 0, stream>>>(
            Pb, Lb, labels, s_t, counts);
    } else {
        dim3 grid((L_LABELS + FBN - 1) / FBN, B_ROWS / FBM);
        count_kernel_slow<<<grid, 256, 0, stream>>>(P, Lab, labels, s_t, counts);
    }

    finalize_kernel<<<1, 256, 0, stream>>>(counts, out);
}